// Round 13
// baseline (104.517 us; speedup 1.0000x reference)
//
#include <hip/hip_runtime.h>

#define IMG_H 1080
#define IMG_W 1920

typedef float f32x4 __attribute__((ext_vector_type(4)));
typedef float f32x2 __attribute__((ext_vector_type(2)));

// Nonzero iff the 16-bit circular mask has 9 consecutive set bits.
// (Equivalent to reference's 24-bit window test; validated absmax=0 R1-R12.)
__device__ __forceinline__ unsigned det9(unsigned m) {
    unsigned x = m | (m << 16);
    unsigned t = x & (x >> 1);   // run 2
    t &= t >> 2;                 // run 4
    t &= t >> 4;                 // run 8
    t &= x >> 8;                 // run 9
    return t;
}

// m = (m << 1) | (val CMP thr) in exactly 2 VALU. Validated R8-R12.
#define STEP_GE(m, sc, val, thr)                                          \
    asm("v_cmp_ge_f32 %1, %2, %3\n\tv_addc_co_u32 %0, %1, %0, %0, %1"     \
        : "+v"(m), "=s"(sc) : "v"(val), "v"(thr))
#define STEP_LE(m, sc, val, thr)                                          \
    asm("v_cmp_le_f32 %1, %2, %3\n\tv_addc_co_u32 %0, %1, %0, %0, %1"     \
        : "+v"(m), "=s"(sc) : "v"(val), "v"(thr))

constexpr int DY[16] = {0, 1, 2, 3, 3, 3, 2, 1, 0, -1, -2, -3, -3, -3, -2, -1};
constexpr int DX[16] = {-3, -3, -2, -1, 0, 1, 2, 3, 3, 3, 2, 1, 0, -1, -2, -3};

__global__ __launch_bounds__(256) void fast_score_kernel(const float* __restrict__ img,
                                                         float* __restrict__ out) {
    const int n  = blockIdx.z;
    const int y  = blockIdx.y;                             // one image row per block
    const int x0 = (blockIdx.x * 256 + threadIdx.x) * 4;   // 4 px per thread
    if (x0 >= IMG_W) return;                               // tail lanes in block 1

    const float* base = img + (size_t)n * (IMG_H * IMG_W);
    float* ob = out + (size_t)n * (IMG_H * IMG_W) + (size_t)y * IMG_W;

    // 7 replicate-clamped row pointers — block-uniform => SGPR pairs.
    const float* rp0 = base + (size_t)min(max(y - 3, 0), IMG_H - 1) * IMG_W;
    const float* rp1 = base + (size_t)min(max(y - 2, 0), IMG_H - 1) * IMG_W;
    const float* rp2 = base + (size_t)min(max(y - 1, 0), IMG_H - 1) * IMG_W;
    const float* rp3 = base + (size_t)y * IMG_W;
    const float* rp4 = base + (size_t)min(y + 1, IMG_H - 1) * IMG_W;
    const float* rp5 = base + (size_t)min(y + 2, IMG_H - 1) * IMG_W;
    const float* rp6 = base + (size_t)min(y + 3, IMG_H - 1) * IMG_W;

    if (x0 >= 4 && x0 <= IMG_W - 8) {
        // ---- interior: 15 vector loads cover all taps for 4 px ----
        const unsigned xm3 = (unsigned)(x0 - 3) * 4u;
        const unsigned xm2 = (unsigned)(x0 - 2) * 4u;
        const unsigned xm1 = (unsigned)(x0 - 1) * 4u;
        const unsigned xc  = (unsigned)(x0)     * 4u;
        const unsigned xp2 = (unsigned)(x0 + 2) * 4u;
        const unsigned xp3 = (unsigned)(x0 + 3) * 4u;

        f32x4 ra3, ra2, ra2b, ra1, ra1b, r0a, r0c, r0b, rc1, rc1b, rc2, rc2b, rc3;
        f32x2 ra3b, rc3b;
        asm volatile(
            "global_load_dwordx4 %0,  %17, %21\n\t"   // ra3  row-3 [x-1..x+2]
            "global_load_dwordx2 %1,  %20, %21\n\t"   // ra3b row-3 [x+3,x+4]
            "global_load_dwordx4 %2,  %16, %22\n\t"   // ra2  row-2 [x-2..x+1]
            "global_load_dwordx4 %3,  %19, %22\n\t"   // ra2b row-2 [x+2..x+5]
            "global_load_dwordx4 %4,  %15, %23\n\t"   // ra1  row-1 [x-3..x]
            "global_load_dwordx4 %5,  %20, %23\n\t"   // ra1b row-1 [x+3..x+6]
            "global_load_dwordx4 %6,  %15, %24\n\t"   // r0a  row 0 [x-3..x]
            "global_load_dwordx4 %7,  %18, %24\n\t"   // r0c  row 0 [x..x+3] centers
            "global_load_dwordx4 %8,  %20, %24\n\t"   // r0b  row 0 [x+3..x+6]
            "global_load_dwordx4 %9,  %15, %25\n\t"   // rc1  row+1 [x-3..x]
            "global_load_dwordx4 %10, %20, %25\n\t"   // rc1b row+1 [x+3..x+6]
            "global_load_dwordx4 %11, %16, %26\n\t"   // rc2  row+2 [x-2..x+1]
            "global_load_dwordx4 %12, %19, %26\n\t"   // rc2b row+2 [x+2..x+5]
            "global_load_dwordx4 %13, %17, %27\n\t"   // rc3  row+3 [x-1..x+2]
            "global_load_dwordx2 %14, %20, %27\n\t"   // rc3b row+3 [x+3,x+4]
            "s_waitcnt vmcnt(0)"
            : "=&v"(ra3), "=&v"(ra3b), "=&v"(ra2), "=&v"(ra2b), "=&v"(ra1),
              "=&v"(ra1b), "=&v"(r0a), "=&v"(r0c), "=&v"(r0b), "=&v"(rc1),
              "=&v"(rc1b), "=&v"(rc2), "=&v"(rc2b), "=&v"(rc3), "=&v"(rc3b)
            : "v"(xm3), "v"(xm2), "v"(xm1), "v"(xc), "v"(xp2), "v"(xp3),
              "s"(rp0), "s"(rp1), "s"(rp2), "s"(rp3), "s"(rp4), "s"(rp5), "s"(rp6));

        float res[4];
#pragma unroll
        for (int p = 0; p < 4; ++p) {
            // row±3 spans: index i = col - (x-1) = p + dx + 1, from {x4, x2} pair
            const float top1 = (p + 0) < 4 ? ra3[p + 0] : ra3b[p - 4];      // dx=-1
            const float top2 = (p + 1) < 4 ? ra3[p + 1] : ra3b[p - 3];      // dx=0
            const float top3 = (p + 2) < 4 ? ra3[p + 2] : ra3b[p - 2];      // dx=+1
            const float bot1 = (p + 0) < 4 ? rc3[p + 0] : rc3b[p - 4];
            const float bot2 = (p + 1) < 4 ? rc3[p + 1] : rc3b[p - 3];
            const float bot3 = (p + 2) < 4 ? rc3[p + 2] : rc3b[p - 2];

            const float t[16] = {
                r0a[p],    // k0  (0,-3)
                rc1[p],    // k1  (1,-3)
                rc2[p],    // k2  (2,-2)
                bot1,      // k3  (3,-1)
                bot2,      // k4  (3, 0)
                bot3,      // k5  (3,+1)
                rc2b[p],   // k6  (2,+2)
                rc1b[p],   // k7  (1,+3)
                r0b[p],    // k8  (0,+3)
                ra1b[p],   // k9  (-1,+3)
                ra2b[p],   // k10 (-2,+2)
                top3,      // k11 (-3,+1)
                top2,      // k12 (-3, 0)
                top1,      // k13 (-3,-1)
                ra2[p],    // k14 (-2,-2)
                ra1[p],    // k15 (-1,-3)
            };
            const float center = r0c[p];
            const float hi = center + 20.0f;
            const float lo = center - 20.0f;
            unsigned dark = 0u, bright = 0u;
            unsigned long long sc0, sc1;
#pragma unroll
            for (int k = 0; k < 16; ++k) {
                STEP_GE(dark,   sc0, t[k], hi);
                STEP_LE(bright, sc1, t[k], lo);
            }
            res[p] = (det9(dark) | det9(bright)) ? 1.0f : 0.0f;
        }
        *(float4*)(ob + x0) = make_float4(res[0], res[1], res[2], res[3]);
    } else {
        // ---- boundary (x0 == 0 or x0 == IMG_W-4): scalar clamped path ----
        const float* rp[7] = {rp0, rp1, rp2, rp3, rp4, rp5, rp6};
#pragma unroll
        for (int p = 0; p < 4; ++p) {
            const int col = x0 + p;
            const float center = rp[3][col];
            float t[16];
#pragma unroll
            for (int k = 0; k < 16; ++k) {
                const int cc = min(max(col + DX[k], 0), IMG_W - 1);
                t[k] = rp[DY[k] + 3][cc];
            }
            const float hi = center + 20.0f;
            const float lo = center - 20.0f;
            unsigned dark = 0u, bright = 0u;
            unsigned long long sc0, sc1;
#pragma unroll
            for (int k = 0; k < 16; ++k) {
                STEP_GE(dark,   sc0, t[k], hi);
                STEP_LE(bright, sc1, t[k], lo);
            }
            ob[col] = (det9(dark) | det9(bright)) ? 1.0f : 0.0f;
        }
    }
}

extern "C" void kernel_launch(void* const* d_in, const int* in_sizes, int n_in,
                              void* d_out, int out_size, void* d_ws, size_t ws_size,
                              hipStream_t stream) {
    const float* img = (const float*)d_in[0];
    float* out = (float*)d_out;
    const int n_img = in_sizes[0] / (IMG_H * IMG_W);   // = 4
    dim3 grid(2,        // 2 x 256 threads x 4 px = 2048 >= 1920 cols
              IMG_H,    // 1080
              n_img);   // 4  -> 8640 blocks
    fast_score_kernel<<<grid, 256, 0, stream>>>(img, out);
}

// Round 14
// 99.604 us; speedup vs baseline: 1.0493x; 1.0493x over previous
//
#include <hip/hip_runtime.h>

#define IMG_H 1080
#define IMG_W 1920

// Nonzero iff the 16-bit circular mask has 9 consecutive set bits.
// (Equivalent to reference's 24-bit window test; validated absmax=0 R1-R13.)
__device__ __forceinline__ unsigned det9(unsigned m) {
    unsigned x = m | (m << 16);
    unsigned t = x & (x >> 1);   // run 2
    t &= t >> 2;                 // run 4
    t &= t >> 4;                 // run 8
    t &= x >> 8;                 // run 9
    return t;
}

// One tap: wait until this tap's load (issue order k, after center) has landed,
// then 4 VALU: cmp+addc for dark, cmp+addc for bright. vmcnt counts oldest-first,
// so vmcnt(15-k) guarantees taps 0..k are in registers.
#define TAP(k, tk)                                                        \
    "s_waitcnt vmcnt(" #k ")\n\t"                                         \
    "v_cmp_ge_f32 %[sd], %[" #tk "], %[hi]\n\t"                           \
    "v_addc_co_u32 %[dk], %[sd], %[dk], %[dk], %[sd]\n\t"                 \
    "v_cmp_le_f32 %[sb], %[" #tk "], %[lo]\n\t"                           \
    "v_addc_co_u32 %[br], %[sb], %[br], %[br], %[sb]\n\t"

__global__ __launch_bounds__(256) void fast_score_kernel(const float* __restrict__ img,
                                                         float* __restrict__ out) {
    const int n  = blockIdx.z;
    const int y  = blockIdx.y;                       // one image row per block
    const int gx = blockIdx.x * 256 + threadIdx.x;   // 0..2047 (loads self-clamp)

    const float* base = img + (size_t)n * (IMG_H * IMG_W);

    // 7 replicate-clamped row pointers — block-uniform => SGPR pairs.
    const float* rp0 = base + (size_t)min(max(y - 3, 0), IMG_H - 1) * IMG_W;
    const float* rp1 = base + (size_t)min(max(y - 2, 0), IMG_H - 1) * IMG_W;
    const float* rp2 = base + (size_t)min(max(y - 1, 0), IMG_H - 1) * IMG_W;
    const float* rp3 = base + (size_t)y * IMG_W;
    const float* rp4 = base + (size_t)min(y + 1, IMG_H - 1) * IMG_W;
    const float* rp5 = base + (size_t)min(y + 2, IMG_H - 1) * IMG_W;
    const float* rp6 = base + (size_t)min(y + 3, IMG_H - 1) * IMG_W;

    // 7 replicate-clamped column BYTE offsets (VGPR)
    unsigned off[7];
#pragma unroll
    for (int d = 0; d < 7; ++d) {
        off[d] = (unsigned)min(max(gx + d - 3, 0), IMG_W - 1) * 4u;
    }

    // Pipelined load+compute: 17 loads issued back-to-back (17 outstanding),
    // then staged vmcnt drains release each tap's 4 VALU as its data lands.
    // Early-clobber everything (R11 lesson: async load dests must not alias inputs).
    unsigned dark, bright;
    float c_, hi_, lo_, t0, t1, t2, t3, t4, t5, t6, t7, t8, t9, t10, t11, t12, t13, t14, t15;
    unsigned long long sd_, sb_;
    asm volatile(
        "global_load_dword %[c],   %[o3], %[r3]\n\t"   // center (issue 0)
        "global_load_dword %[p0],  %[o0], %[r3]\n\t"   // k0  (0,-3)
        "global_load_dword %[p1],  %[o0], %[r4]\n\t"   // k1  (1,-3)
        "global_load_dword %[p2],  %[o1], %[r5]\n\t"   // k2  (2,-2)
        "global_load_dword %[p3],  %[o2], %[r6]\n\t"   // k3  (3,-1)
        "global_load_dword %[p4],  %[o3], %[r6]\n\t"   // k4  (3, 0)
        "global_load_dword %[p5],  %[o4], %[r6]\n\t"   // k5  (3,+1)
        "global_load_dword %[p6],  %[o5], %[r5]\n\t"   // k6  (2,+2)
        "global_load_dword %[p7],  %[o6], %[r4]\n\t"   // k7  (1,+3)
        "global_load_dword %[p8],  %[o6], %[r3]\n\t"   // k8  (0,+3)
        "global_load_dword %[p9],  %[o6], %[r2]\n\t"   // k9  (-1,+3)
        "global_load_dword %[p10], %[o5], %[r1]\n\t"   // k10 (-2,+2)
        "global_load_dword %[p11], %[o4], %[r0]\n\t"   // k11 (-3,+1)
        "global_load_dword %[p12], %[o3], %[r0]\n\t"   // k12 (-3, 0)
        "global_load_dword %[p13], %[o2], %[r0]\n\t"   // k13 (-3,-1)
        "global_load_dword %[p14], %[o1], %[r1]\n\t"   // k14 (-2,-2)
        "global_load_dword %[p15], %[o0], %[r2]\n\t"   // k15 (-1,-3)
        "v_mov_b32 %[dk], 0\n\t"
        "v_mov_b32 %[br], 0\n\t"
        "s_waitcnt vmcnt(16)\n\t"                      // center landed
        "v_add_f32 %[hi], 0x41a00000, %[c]\n\t"        // hi = center + 20.0
        "v_subrev_f32 %[lo], 0x41a00000, %[c]\n\t"     // lo = center - 20.0
        TAP(15, p0)  TAP(14, p1)  TAP(13, p2)  TAP(12, p3)
        TAP(11, p4)  TAP(10, p5)  TAP(9,  p6)  TAP(8,  p7)
        TAP(7,  p8)  TAP(6,  p9)  TAP(5,  p10) TAP(4,  p11)
        TAP(3,  p12) TAP(2,  p13) TAP(1,  p14) TAP(0,  p15)
        : [dk] "=&v"(dark), [br] "=&v"(bright),
          [c] "=&v"(c_), [hi] "=&v"(hi_), [lo] "=&v"(lo_),
          [p0] "=&v"(t0), [p1] "=&v"(t1), [p2] "=&v"(t2), [p3] "=&v"(t3),
          [p4] "=&v"(t4), [p5] "=&v"(t5), [p6] "=&v"(t6), [p7] "=&v"(t7),
          [p8] "=&v"(t8), [p9] "=&v"(t9), [p10] "=&v"(t10), [p11] "=&v"(t11),
          [p12] "=&v"(t12), [p13] "=&v"(t13), [p14] "=&v"(t14), [p15] "=&v"(t15),
          [sd] "=&s"(sd_), [sb] "=&s"(sb_)
        : [o0] "v"(off[0]), [o1] "v"(off[1]), [o2] "v"(off[2]), [o3] "v"(off[3]),
          [o4] "v"(off[4]), [o5] "v"(off[5]), [o6] "v"(off[6]),
          [r0] "s"(rp0), [r1] "s"(rp1), [r2] "s"(rp2), [r3] "s"(rp3),
          [r4] "s"(rp4), [r5] "s"(rp5), [r6] "s"(rp6));

    // Note: mask bit order is k-reversed vs reference (addc appends at LSB),
    // which is a reflection — run-of-9 existence is invariant. Validated R8-R13.
    const float res = (det9(dark) | det9(bright)) ? 1.0f : 0.0f;
    if (gx < IMG_W) {
        out[(size_t)n * (IMG_H * IMG_W) + (size_t)y * IMG_W + gx] = res;
    }
}

extern "C" void kernel_launch(void* const* d_in, const int* in_sizes, int n_in,
                              void* d_out, int out_size, void* d_ws, size_t ws_size,
                              hipStream_t stream) {
    const float* img = (const float*)d_in[0];
    float* out = (float*)d_out;
    const int n_img = in_sizes[0] / (IMG_H * IMG_W);   // = 4
    dim3 grid((IMG_W + 255) / 256,   // 8
              IMG_H,                 // 1080
              n_img);                // 4  -> 34560 blocks
    fast_score_kernel<<<grid, 256, 0, stream>>>(img, out);
}